// Round 1
// baseline (6639.006 us; speedup 1.0000x reference)
//
#include <hip/hip_runtime.h>

// ---------------------------------------------------------------------------
// Model dims (fixed): L=4 B=4 S=256 D=1024 H=16 DN=64 DR=32 DV=64
// RQ=384 RKV=256 E=8 K=2 M=512 MS=2048 F_IN=64; T = B*S = 1024 tokens.
// ---------------------------------------------------------------------------

#define SCALE_ATTN 0.10206207261596577f  // 1/sqrt(96)

// ---------------- RMS norm: out = x * rsqrt(mean(x^2)+eps) * w -------------
__global__ __launch_bounds__(256) void k_rms(
    const float* __restrict__ in, int in_stride,
    const float* __restrict__ w,
    float* __restrict__ out, int out_stride, int width) {
  int row = blockIdx.x;
  const float* x = in + (size_t)row * in_stride;
  float ss = 0.f;
  for (int i = threadIdx.x; i < width; i += 256) { float v = x[i]; ss += v * v; }
  __shared__ float red[256];
  red[threadIdx.x] = ss;
  __syncthreads();
  #pragma unroll
  for (int s = 128; s > 0; s >>= 1) {
    if (threadIdx.x < s) red[threadIdx.x] += red[threadIdx.x + s];
    __syncthreads();
  }
  float inv = rsqrtf(red[0] / (float)width + 1e-6f);
  float* o = out + (size_t)row * out_stride;
  for (int i = threadIdx.x; i < width; i += 256) o[i] = x[i] * inv * w[i];
}

// ------------- dense GEMM: C[M,N] = A[M,K] @ B[K,N] (+ optional R) ---------
// Requires M%128==0, K%16==0, N%4==0. 128x128 block tile, 8x8 per thread.
__global__ __launch_bounds__(256) void k_gemm(
    const float* __restrict__ A, const float* __restrict__ B,
    float* __restrict__ C, const float* __restrict__ R,
    int M, int N, int Kd) {
  __shared__ float As[16][132];  // transposed A tile [k][m]
  __shared__ float Bs[16][136];
  const int bm = blockIdx.y << 7, bn = blockIdx.x << 7;
  const int tid = threadIdx.x, tx = tid & 15, ty = tid >> 4;
  float acc[8][8] = {};
  for (int k0 = 0; k0 < Kd; k0 += 16) {
    #pragma unroll
    for (int t = 0; t < 2; t++) {
      int c = tid + (t << 8);
      int r = c >> 2, kc = (c & 3) << 2;
      float4 v = *(const float4*)(A + (size_t)(bm + r) * Kd + k0 + kc);
      As[kc + 0][r] = v.x; As[kc + 1][r] = v.y;
      As[kc + 2][r] = v.z; As[kc + 3][r] = v.w;
    }
    #pragma unroll
    for (int t = 0; t < 2; t++) {
      int c = tid + (t << 8);
      int r = c >> 5, c4 = (c & 31) << 2;
      int gc = bn + c4;
      float4 v = make_float4(0.f, 0.f, 0.f, 0.f);
      if (gc < N) v = *(const float4*)(B + (size_t)(k0 + r) * N + gc);
      *(float4*)&Bs[r][c4] = v;
    }
    __syncthreads();
    #pragma unroll
    for (int kk = 0; kk < 16; kk++) {
      float4 A0 = *(const float4*)&As[kk][ty << 2];
      float4 A1 = *(const float4*)&As[kk][64 + (ty << 2)];
      float4 B0 = *(const float4*)&Bs[kk][tx << 2];
      float4 B1 = *(const float4*)&Bs[kk][64 + (tx << 2)];
      float va[8] = {A0.x, A0.y, A0.z, A0.w, A1.x, A1.y, A1.z, A1.w};
      float vb[8] = {B0.x, B0.y, B0.z, B0.w, B1.x, B1.y, B1.z, B1.w};
      #pragma unroll
      for (int i = 0; i < 8; i++)
        #pragma unroll
        for (int j = 0; j < 8; j++)
          acc[i][j] = fmaf(va[i], vb[j], acc[i][j]);
    }
    __syncthreads();
  }
  #pragma unroll
  for (int i = 0; i < 8; i++) {
    int row = bm + ((i >> 2) << 6) + (ty << 2) + (i & 3);
    float* Crow = C + (size_t)row * N;
    #pragma unroll
    for (int jb = 0; jb < 2; jb++) {
      int gc = bn + (jb << 6) + (tx << 2);
      if (gc < N) {
        float4 o;
        o.x = acc[i][jb * 4 + 0]; o.y = acc[i][jb * 4 + 1];
        o.z = acc[i][jb * 4 + 2]; o.w = acc[i][jb * 4 + 3];
        if (R) {
          float4 rv = *(const float4*)(R + (size_t)row * N + gc);
          o.x += rv.x; o.y += rv.y; o.z += rv.z; o.w += rv.w;
        }
        *(float4*)(Crow + gc) = o;
      }
    }
  }
}

// --------- grouped (per-expert) GEMM with optional row gather --------------
// Out[off_e + r, :] = A[row(r), :K] @ Wbase[e][:K, :N],  r < counts[e]
// row(r) = gather[off_e + r] if gather else off_e + r. N%64==0, K%16==0.
__global__ __launch_bounds__(256) void k_ggemm(
    const float* __restrict__ A, int lda, const int* __restrict__ gather,
    const int* __restrict__ offs, const int* __restrict__ counts,
    const float* __restrict__ Wbase, long wstride, int Kd, int N,
    float* __restrict__ Out) {
  const int e = blockIdx.z;
  const int cnt = counts[e];
  const int rt = blockIdx.y << 6;
  if (rt >= cnt) return;
  const int off = offs[e];
  const float* Bp = Wbase + (size_t)e * wstride;
  const int bn = blockIdx.x << 6;
  __shared__ float As[16][68];
  __shared__ float Bs[16][68];
  const int tid = threadIdx.x, tx = tid & 15, ty = tid >> 4;
  float acc[4][4] = {};
  const int lr = tid >> 2, kc = (tid & 3) << 2;
  int arow = -1;
  if (rt + lr < cnt) arow = gather ? gather[off + rt + lr] : (off + rt + lr);
  const int br = tid >> 4, bc = (tid & 15) << 2;
  for (int k0 = 0; k0 < Kd; k0 += 16) {
    float4 va = make_float4(0.f, 0.f, 0.f, 0.f);
    if (arow >= 0) va = *(const float4*)(A + (size_t)arow * lda + k0 + kc);
    As[kc + 0][lr] = va.x; As[kc + 1][lr] = va.y;
    As[kc + 2][lr] = va.z; As[kc + 3][lr] = va.w;
    float4 vb = *(const float4*)(Bp + (size_t)(k0 + br) * N + bn + bc);
    *(float4*)&Bs[br][bc] = vb;
    __syncthreads();
    #pragma unroll
    for (int kk = 0; kk < 16; kk++) {
      float4 a4 = *(const float4*)&As[kk][ty << 2];
      float4 b4 = *(const float4*)&Bs[kk][tx << 2];
      float va_[4] = {a4.x, a4.y, a4.z, a4.w};
      float vb_[4] = {b4.x, b4.y, b4.z, b4.w};
      #pragma unroll
      for (int i = 0; i < 4; i++)
        #pragma unroll
        for (int j = 0; j < 4; j++)
          acc[i][j] = fmaf(va_[i], vb_[j], acc[i][j]);
    }
    __syncthreads();
  }
  #pragma unroll
  for (int i = 0; i < 4; i++) {
    int r = rt + (ty << 2) + i;
    if (r < cnt) {
      float4 o;
      o.x = acc[i][0]; o.y = acc[i][1]; o.z = acc[i][2]; o.w = acc[i][3];
      *(float4*)(Out + (size_t)(off + r) * N + bn + (tx << 2)) = o;
    }
  }
}

// ---------------- rope: q[..., 64:96] per head (in-place) + k_pe -----------
__global__ __launch_bounds__(256) void k_rope(
    float* __restrict__ q, const float* __restrict__ kva, float* __restrict__ kp,
    const float* __restrict__ cosb, const float* __restrict__ sinb) {
  int gid = blockIdx.x * 256 + threadIdx.x;
  if (gid >= 1024 * 17 * 16) return;
  int i = gid & 15;
  int rem = gid >> 4;
  int hh = rem % 17;
  int t = rem / 17;
  int s = t & 255;
  float c = cosb[s * 16 + i], sn = sinb[s * 16 + i];
  if (hh < 16) {
    float* p = q + (size_t)t * 1536 + hh * 96 + 64 + 2 * i;
    float a = p[0], bb = p[1];
    p[0] = a * c - bb * sn;
    p[1] = a * sn + bb * c;
  } else {
    const float* p = kva + (size_t)t * 288 + 256 + 2 * i;
    float a = p[0], bb = p[1];
    kp[t * 32 + 2 * i] = a * c - bb * sn;
    kp[t * 32 + 2 * i + 1] = a * sn + bb * c;
  }
}

// ---------------- flash attention, 32 q-rows x 64-key tiles ----------------
// grid (S/32, H, B). q:[T,H*96] (rope applied), kv:[T,H*128], kp:[T,32]
__global__ __launch_bounds__(256) void k_attn(
    const float* __restrict__ q, const float* __restrict__ kv,
    const float* __restrict__ kp, float* __restrict__ out) {
  const int qt = blockIdx.x, h = blockIdx.y, b = blockIdx.z;
  __shared__ float Qs[32][97];
  __shared__ float Ks[64][97];
  __shared__ float Vs[64][65];
  __shared__ float Ps[32][65];
  const int tid = threadIdx.x, tx = tid & 15, ty = tid >> 4;
  const int qrow0 = b * 256 + qt * 32;
  for (int idx = tid; idx < 32 * 24; idx += 256) {
    int r = idx / 24, c4 = (idx % 24) << 2;
    float4 v = *(const float4*)(q + (size_t)(qrow0 + r) * 1536 + h * 96 + c4);
    Qs[r][c4 + 0] = v.x * SCALE_ATTN; Qs[r][c4 + 1] = v.y * SCALE_ATTN;
    Qs[r][c4 + 2] = v.z * SCALE_ATTN; Qs[r][c4 + 3] = v.w * SCALE_ATTN;
  }
  float acc[2][4] = {};
  float mrow[2] = {-1e30f, -1e30f};
  float lrow[2] = {0.f, 0.f};
  const int nkt = (qt * 32 + 31) / 64 + 1;
  for (int kt = 0; kt < nkt; kt++) {
    __syncthreads();  // protects Qs (first iter) and Ks/Vs/Ps reuse
    const int krow0 = b * 256 + kt * 64;
    for (int idx = tid; idx < 64 * 16; idx += 256) {
      int r = idx >> 4, c4 = (idx & 15) << 2;
      float4 v = *(const float4*)(kv + (size_t)(krow0 + r) * 2048 + h * 128 + c4);
      Ks[r][c4 + 0] = v.x; Ks[r][c4 + 1] = v.y; Ks[r][c4 + 2] = v.z; Ks[r][c4 + 3] = v.w;
    }
    for (int idx = tid; idx < 64 * 8; idx += 256) {
      int r = idx >> 3, c4 = (idx & 7) << 2;
      float4 v = *(const float4*)(kp + (size_t)(krow0 + r) * 32 + c4);
      Ks[r][64 + c4 + 0] = v.x; Ks[r][64 + c4 + 1] = v.y;
      Ks[r][64 + c4 + 2] = v.z; Ks[r][64 + c4 + 3] = v.w;
    }
    for (int idx = tid; idx < 64 * 16; idx += 256) {
      int r = idx >> 4, c4 = (idx & 15) << 2;
      float4 v = *(const float4*)(kv + (size_t)(krow0 + r) * 2048 + h * 128 + 64 + c4);
      Vs[r][c4 + 0] = v.x; Vs[r][c4 + 1] = v.y; Vs[r][c4 + 2] = v.z; Vs[r][c4 + 3] = v.w;
    }
    __syncthreads();
    float s[2][4] = {};
    for (int d = 0; d < 96; d++) {
      float a0 = Qs[(ty << 1) + 0][d];
      float a1 = Qs[(ty << 1) + 1][d];
      float b0 = Ks[(tx << 2) + 0][d];
      float b1 = Ks[(tx << 2) + 1][d];
      float b2 = Ks[(tx << 2) + 2][d];
      float b3 = Ks[(tx << 2) + 3][d];
      s[0][0] = fmaf(a0, b0, s[0][0]); s[0][1] = fmaf(a0, b1, s[0][1]);
      s[0][2] = fmaf(a0, b2, s[0][2]); s[0][3] = fmaf(a0, b3, s[0][3]);
      s[1][0] = fmaf(a1, b0, s[1][0]); s[1][1] = fmaf(a1, b1, s[1][1]);
      s[1][2] = fmaf(a1, b2, s[1][2]); s[1][3] = fmaf(a1, b3, s[1][3]);
    }
    #pragma unroll
    for (int i = 0; i < 2; i++) {
      int qg = qt * 32 + (ty << 1) + i;
      #pragma unroll
      for (int j = 0; j < 4; j++) {
        int kg = kt * 64 + (tx << 2) + j;
        if (kg > qg) s[i][j] = -1e30f;  // exp underflows to exactly 0
      }
    }
    #pragma unroll
    for (int i = 0; i < 2; i++) {
      float mx = fmaxf(fmaxf(s[i][0], s[i][1]), fmaxf(s[i][2], s[i][3]));
      mx = fmaxf(mx, __shfl_xor(mx, 1));
      mx = fmaxf(mx, __shfl_xor(mx, 2));
      mx = fmaxf(mx, __shfl_xor(mx, 4));
      mx = fmaxf(mx, __shfl_xor(mx, 8));
      float mnew = fmaxf(mrow[i], mx);
      float sc = expf(mrow[i] - mnew);
      float psum = 0.f;
      #pragma unroll
      for (int j = 0; j < 4; j++) {
        float p = expf(s[i][j] - mnew);
        Ps[(ty << 1) + i][(tx << 2) + j] = p;
        psum += p;
      }
      psum += __shfl_xor(psum, 1);
      psum += __shfl_xor(psum, 2);
      psum += __shfl_xor(psum, 4);
      psum += __shfl_xor(psum, 8);
      lrow[i] = lrow[i] * sc + psum;
      mrow[i] = mnew;
      #pragma unroll
      for (int j = 0; j < 4; j++) acc[i][j] *= sc;
    }
    __syncthreads();
    for (int kc = 0; kc < 64; kc++) {
      float p0 = Ps[(ty << 1) + 0][kc];
      float p1 = Ps[(ty << 1) + 1][kc];
      float v0 = Vs[kc][(tx << 2) + 0];
      float v1 = Vs[kc][(tx << 2) + 1];
      float v2 = Vs[kc][(tx << 2) + 2];
      float v3 = Vs[kc][(tx << 2) + 3];
      acc[0][0] = fmaf(p0, v0, acc[0][0]); acc[0][1] = fmaf(p0, v1, acc[0][1]);
      acc[0][2] = fmaf(p0, v2, acc[0][2]); acc[0][3] = fmaf(p0, v3, acc[0][3]);
      acc[1][0] = fmaf(p1, v0, acc[1][0]); acc[1][1] = fmaf(p1, v1, acc[1][1]);
      acc[1][2] = fmaf(p1, v2, acc[1][2]); acc[1][3] = fmaf(p1, v3, acc[1][3]);
    }
  }
  #pragma unroll
  for (int i = 0; i < 2; i++) {
    float inv = 1.f / lrow[i];
    float4 o;
    o.x = acc[i][0] * inv; o.y = acc[i][1] * inv;
    o.z = acc[i][2] * inv; o.w = acc[i][3] * inv;
    *(float4*)(out + (size_t)(qrow0 + (ty << 1) + i) * 1024 + h * 64 + (tx << 2)) = o;
  }
}

// ---------------- router: logits, softmax, top-2, counts -------------------
__global__ __launch_bounds__(256) void k_router(
    const float* __restrict__ t_, const float* __restrict__ Wr,
    int* __restrict__ tok_idx, float* __restrict__ tok_w, int* __restrict__ counts) {
  int wv = threadIdx.x >> 6, lane = threadIdx.x & 63;
  int tok = blockIdx.x * 4 + wv;
  const float* x = t_ + (size_t)tok * 1024;
  float a[8] = {};
  for (int d = lane; d < 1024; d += 64) {
    float xv = x[d];
    const float* wr = Wr + d * 8;
    #pragma unroll
    for (int e = 0; e < 8; e++) a[e] = fmaf(xv, wr[e], a[e]);
  }
  #pragma unroll
  for (int e = 0; e < 8; e++) {
    #pragma unroll
    for (int off = 32; off > 0; off >>= 1) a[e] += __shfl_xor(a[e], off);
  }
  if (lane == 0) {
    float m = a[0];
    #pragma unroll
    for (int e = 1; e < 8; e++) m = fmaxf(m, a[e]);
    float p[8];
    #pragma unroll
    for (int e = 0; e < 8; e++) p[e] = expf(a[e] - m);
    int i0 = 0;
    #pragma unroll
    for (int e = 1; e < 8; e++) if (p[e] > p[i0]) i0 = e;
    int i1 = (i0 == 0) ? 1 : 0;
    #pragma unroll
    for (int e = 0; e < 8; e++) if (e != i0 && p[e] > p[i1]) i1 = e;
    float denom = p[i0] + p[i1];
    tok_idx[tok * 2] = i0; tok_idx[tok * 2 + 1] = i1;
    tok_w[tok * 2] = p[i0] / denom; tok_w[tok * 2 + 1] = p[i1] / denom;
    atomicAdd(&counts[i0], 1);
    atomicAdd(&counts[i1], 1);
  }
}

__global__ void k_zero8(int* counts) { if (threadIdx.x < 8) counts[threadIdx.x] = 0; }

__global__ void k_scan(const int* __restrict__ counts, int* __restrict__ offs,
                       int* __restrict__ cursor) {
  if (threadIdx.x == 0) {
    int s = 0;
    for (int e = 0; e < 8; e++) { offs[e] = s; cursor[e] = s; s += counts[e]; }
  }
}

__global__ __launch_bounds__(256) void k_assign(
    const int* __restrict__ tok_idx, int* __restrict__ cursor,
    int* __restrict__ gather, int* __restrict__ pos) {
  int t = blockIdx.x * 256 + threadIdx.x;
  if (t >= 1024) return;
  #pragma unroll
  for (int s2 = 0; s2 < 2; s2++) {
    int e = tok_idx[t * 2 + s2];
    int p = atomicAdd(&cursor[e], 1);
    gather[p] = t;
    pos[t * 2 + s2] = p;
  }
}

__global__ __launch_bounds__(256) void k_silu_mul(
    const float* __restrict__ g1, const float* __restrict__ g3,
    float* __restrict__ o, int n) {
  for (int i = blockIdx.x * 256 + threadIdx.x; i < n; i += gridDim.x * 256) {
    float x = g1[i];
    o[i] = (x / (1.f + expf(-x))) * g3[i];
  }
}

__global__ __launch_bounds__(256) void k_combine(
    float* __restrict__ hs, const float* __restrict__ sho,
    const float* __restrict__ routed, const int* __restrict__ pos,
    const float* __restrict__ tok_w) {
  int i = blockIdx.x * 256 + threadIdx.x;
  if (i >= 1024 * 1024) return;
  int t = i >> 10, d = i & 1023;
  float v = hs[i] + sho[i];
  v = fmaf(tok_w[t * 2], routed[(size_t)pos[t * 2] * 1024 + d], v);
  v = fmaf(tok_w[t * 2 + 1], routed[(size_t)pos[t * 2 + 1] * 1024 + d], v);
  hs[i] = v;
}

__global__ __launch_bounds__(256) void k_outproj(
    const float* __restrict__ h, const float* __restrict__ W, float* __restrict__ out) {
  int t = blockIdx.x;
  float s = 0.f;
  for (int d = threadIdx.x; d < 1024; d += 256) s = fmaf(h[(size_t)t * 1024 + d], W[d], s);
  __shared__ float red[256];
  red[threadIdx.x] = s;
  __syncthreads();
  #pragma unroll
  for (int st = 128; st > 0; st >>= 1) {
    if (threadIdx.x < st) red[threadIdx.x] += red[threadIdx.x + st];
    __syncthreads();
  }
  if (threadIdx.x == 0) out[t] = red[0];
}

// ---------------------------------------------------------------------------
extern "C" void kernel_launch(void* const* d_in, const int* in_sizes, int n_in,
                              void* d_out, int out_size, void* d_ws, size_t ws_size,
                              hipStream_t stream) {
  (void)in_sizes; (void)n_in; (void)out_size; (void)ws_size;
  const float* x        = (const float*)d_in[0];
  const float* rope_cos = (const float*)d_in[1];
  const float* rope_sin = (const float*)d_in[2];
  const float* W_in     = (const float*)d_in[3];
  const float* attn_nw  = (const float*)d_in[4];
  const float* Wqa      = (const float*)d_in[5];
  const float* q_nw     = (const float*)d_in[6];
  const float* Wqb      = (const float*)d_in[7];
  const float* Wkva     = (const float*)d_in[8];
  const float* kv_nw    = (const float*)d_in[9];
  const float* Wkvb     = (const float*)d_in[10];
  const float* Wo       = (const float*)d_in[11];
  const float* moe_nw   = (const float*)d_in[12];
  const float* Wr       = (const float*)d_in[13];
  const float* We1      = (const float*)d_in[14];
  const float* We3      = (const float*)d_in[15];
  const float* We2      = (const float*)d_in[16];
  const float* Ws1      = (const float*)d_in[17];
  const float* Ws3      = (const float*)d_in[18];
  const float* Ws2      = (const float*)d_in[19];
  const float* fin_nw   = (const float*)d_in[20];
  const float* W_out    = (const float*)d_in[21];
  float* out = (float*)d_out;

  // ---- workspace layout (floats); attn/MoE phases alias the arena ----
  float* W  = (float*)d_ws;
  float* hs = W;                       // 1048576
  float* h  = hs + 1048576;            // 1048576
  float* ar = h + 1048576;
  // attention phase
  float* qa   = ar;                    // 1024*384
  float* q    = qa + 393216;           // 1024*1536
  float* kva  = q + 1572864;           // 1024*288
  float* ckv  = kva + 294912;          // 1024*256
  float* kv   = ckv + 262144;          // 1024*2048
  float* kp   = kv + 2097152;          // 1024*32
  float* attn = kp + 32768;            // 1024*1024
  // MoE phase (aliases attention phase)
  float* g1     = ar;                  // 2048*512
  float* g3     = g1 + 1048576;        // 2048*512
  float* routed = g3 + 1048576;        // 2048*1024
  float* s1     = routed + 2097152;    // 1024*2048
  float* s3     = s1 + 2097152;        // 1024*2048
  float* sho    = s3 + 2097152;        // 1024*1024
  float* arena_end = ar + 9437184;
  int*   counts  = (int*)arena_end;
  int*   offs    = counts + 8;
  int*   cursor  = offs + 8;
  int*   tok_idx = cursor + 8;         // 2048
  int*   pos     = tok_idx + 2048;     // 2048
  int*   gatherA = pos + 2048;         // 2048
  float* tok_w   = (float*)(gatherA + 2048);  // 2048

  dim3 thr(256);

  // hs = x @ W_in   (1024x64 @ 64x1024)
  k_gemm<<<dim3(8, 8), thr, 0, stream>>>(x, W_in, hs, nullptr, 1024, 1024, 64);

  for (int l = 0; l < 4; l++) {
    // ---- attention block ----
    k_rms<<<1024, thr, 0, stream>>>(hs, 1024, attn_nw + l * 1024, h, 1024, 1024);
    k_gemm<<<dim3(3, 8), thr, 0, stream>>>(h, Wqa + (size_t)l * 393216, qa, nullptr, 1024, 384, 1024);
    k_rms<<<1024, thr, 0, stream>>>(qa, 384, q_nw + l * 384, qa, 384, 384);
    k_gemm<<<dim3(12, 8), thr, 0, stream>>>(qa, Wqb + (size_t)l * 589824, q, nullptr, 1024, 1536, 384);
    k_gemm<<<dim3(3, 8), thr, 0, stream>>>(h, Wkva + (size_t)l * 294912, kva, nullptr, 1024, 288, 1024);
    k_rms<<<1024, thr, 0, stream>>>(kva, 288, kv_nw + l * 256, ckv, 256, 256);
    k_gemm<<<dim3(16, 8), thr, 0, stream>>>(ckv, Wkvb + (size_t)l * 524288, kv, nullptr, 1024, 2048, 256);
    k_rope<<<1088, thr, 0, stream>>>(q, kva, kp, rope_cos, rope_sin);
    k_attn<<<dim3(8, 16, 4), thr, 0, stream>>>(q, kv, kp, attn);
    k_gemm<<<dim3(8, 8), thr, 0, stream>>>(attn, Wo + (size_t)l * 1048576, hs, hs, 1024, 1024, 1024);

    // ---- MoE block ----
    k_rms<<<1024, thr, 0, stream>>>(hs, 1024, moe_nw + l * 1024, h, 1024, 1024);
    k_zero8<<<1, 64, 0, stream>>>(counts);
    k_router<<<256, thr, 0, stream>>>(h, Wr + (size_t)l * 8192, tok_idx, tok_w, counts);
    k_scan<<<1, 64, 0, stream>>>(counts, offs, cursor);
    k_assign<<<4, thr, 0, stream>>>(tok_idx, cursor, gatherA, pos);
    k_ggemm<<<dim3(8, 16, 8), thr, 0, stream>>>(h, 1024, gatherA, offs, counts,
        We1 + (size_t)l * 4194304, 524288L, 1024, 512, g1);
    k_ggemm<<<dim3(8, 16, 8), thr, 0, stream>>>(h, 1024, gatherA, offs, counts,
        We3 + (size_t)l * 4194304, 524288L, 1024, 512, g3);
    k_silu_mul<<<1024, thr, 0, stream>>>(g1, g3, g1, 2048 * 512);
    k_ggemm<<<dim3(16, 16, 8), thr, 0, stream>>>(g1, 512, nullptr, offs, counts,
        We2 + (size_t)l * 4194304, 524288L, 512, 1024, routed);
    k_gemm<<<dim3(16, 8), thr, 0, stream>>>(h, Ws1 + (size_t)l * 2097152, s1, nullptr, 1024, 2048, 1024);
    k_gemm<<<dim3(16, 8), thr, 0, stream>>>(h, Ws3 + (size_t)l * 2097152, s3, nullptr, 1024, 2048, 1024);
    k_silu_mul<<<2048, thr, 0, stream>>>(s1, s3, s1, 1024 * 2048);
    k_gemm<<<dim3(8, 8), thr, 0, stream>>>(s1, Ws2 + (size_t)l * 2097152, sho, nullptr, 1024, 1024, 2048);
    k_combine<<<4096, thr, 0, stream>>>(hs, sho, routed, pos, tok_w);
  }

  // ---- final norm + output projection ----
  k_rms<<<1024, thr, 0, stream>>>(hs, 1024, fin_nw, h, 1024, 1024);
  k_outproj<<<1024, thr, 0, stream>>>(h, W_out, out);
}

// Round 3
// 2367.958 us; speedup vs baseline: 2.8037x; 2.8037x over previous
//
#include <hip/hip_runtime.h>

// ---------------------------------------------------------------------------
// Model dims (fixed): L=4 B=4 S=256 D=1024 H=16 DN=64 DR=32 DV=64
// RQ=384 RKV=256 E=8 K=2 M=512 MS=2048 F_IN=64; T = B*S = 1024 tokens.
// GEMMs run as split-bf16 (hi+lo) MFMA: C = Ah*Bh + Ah*Bl + Al*Bh (fp32 acc).
// Weights converted per-layer in 3 phases into a 50.3 MB scratch; total
// workspace ~96.8 MB.
// ---------------------------------------------------------------------------

#define SCALE_ATTN 0.10206207261596577f  // 1/sqrt(96)

typedef __attribute__((ext_vector_type(8))) short bf16x8;
typedef __attribute__((ext_vector_type(4))) float f32x4;

// round-to-nearest-even split of fp32 into bf16 hi + bf16 lo
__device__ __forceinline__ void split2(float x, unsigned& h, unsigned& l) {
  unsigned u = __builtin_bit_cast(unsigned, x);
  unsigned hr = (u + 0x7FFFu + ((u >> 16) & 1u)) & 0xFFFF0000u;
  float hf = __builtin_bit_cast(float, hr);
  h = hr >> 16;
  float r = x - hf;
  unsigned ur = __builtin_bit_cast(unsigned, r);
  l = (ur + 0x7FFFu + ((ur >> 16) & 1u)) >> 16;
}

// ---------------- RMS norm ------------------------------------------------
__global__ __launch_bounds__(256) void k_rms(
    const float* __restrict__ in, int in_stride,
    const float* __restrict__ w,
    float* __restrict__ out, int out_stride, int width) {
  int row = blockIdx.x;
  const float* x = in + (size_t)row * in_stride;
  float ss = 0.f;
  for (int i = threadIdx.x; i < width; i += 256) { float v = x[i]; ss += v * v; }
  __shared__ float red[256];
  red[threadIdx.x] = ss;
  __syncthreads();
  #pragma unroll
  for (int s = 128; s > 0; s >>= 1) {
    if (threadIdx.x < s) red[threadIdx.x] += red[threadIdx.x + s];
    __syncthreads();
  }
  float inv = rsqrtf(red[0] / (float)width + 1e-6f);
  float* o = out + (size_t)row * out_stride;
  for (int i = threadIdx.x; i < width; i += 256) o[i] = x[i] * inv * w[i];
}

// --------- weight convert: W[K][N] fp32 -> Wt_hi/Wt_lo [Npad][K] bf16 ------
// Padded rows (gn >= N) are written as zeros (ws is poisoned 0xAA).
struct CvDesc {
  const float* src;
  unsigned short* dh;
  unsigned short* dl;
  int K, N, sst, dst;     // strides in elements (per batch matrix)
  int tile0, tpm, ktiles; // tile prefix, tiles per matrix, K/32
};
struct CvArgs { CvDesc d[6]; int nd; };

__global__ __launch_bounds__(256) void k_conv(CvArgs a) {
  int bid = blockIdx.x;
  int di = 0;
  while (di + 1 < a.nd && bid >= a.d[di + 1].tile0) di++;
  const CvDesc dd = a.d[di];
  int t = bid - dd.tile0;
  int mat = t / dd.tpm, tt = t - mat * dd.tpm;
  int kt = tt % dd.ktiles, nt = tt / dd.ktiles;
  const float* src = dd.src + (size_t)mat * dd.sst;
  __shared__ float L[32][33];
  int tid = threadIdx.x;
  {
    int kl = tid >> 3, nl4 = (tid & 7) << 2;
    int gn = nt * 32 + nl4;
    float4 v = make_float4(0.f, 0.f, 0.f, 0.f);
    if (gn < dd.N) v = *(const float4*)(src + (size_t)(kt * 32 + kl) * dd.N + gn);
    L[nl4 + 0][kl] = v.x; L[nl4 + 1][kl] = v.y;
    L[nl4 + 2][kl] = v.z; L[nl4 + 3][kl] = v.w;
  }
  __syncthreads();
  int nr = tid >> 3, kc = (tid & 7) << 2;
  unsigned h0, h1, h2, h3, l0, l1, l2, l3;
  split2(L[nr][kc + 0], h0, l0);
  split2(L[nr][kc + 1], h1, l1);
  split2(L[nr][kc + 2], h2, l2);
  split2(L[nr][kc + 3], h3, l3);
  size_t o = (size_t)mat * dd.dst + (size_t)(nt * 32 + nr) * dd.K + kt * 32 + kc;
  uint2 hp, lp;
  hp.x = h0 | (h1 << 16); hp.y = h2 | (h3 << 16);
  lp.x = l0 | (l1 << 16); lp.y = l2 | (l3 << 16);
  *(uint2*)(dd.dh + o) = hp;
  *(uint2*)(dd.dl + o) = lp;
}

// --------- unified dense/grouped split-bf16 MFMA GEMM ----------------------
// C[off+r, :N] = A[row(r), :K] @ B_e  where B stored as [Npad][K] bf16 hi/lo.
// BM=64, BN=128, BK=32; 256 thr = 4 waves (2x2), wave tile 32x64.
// dense: counts==nullptr -> cnt=M, off=0, row(r)=r.
// grouped: cnt=counts[e], off=offs[e], row(r)=gather?gather[off+r]:off+r.
__global__ __launch_bounds__(256) void k_gsp(
    const float* __restrict__ A, int lda,
    const int* __restrict__ gather, const int* __restrict__ offs,
    const int* __restrict__ counts,
    const unsigned short* __restrict__ Bh, const unsigned short* __restrict__ Bl,
    long wstride, int K, int N, int M,
    float* __restrict__ C, int ldc, const float* __restrict__ R) {
  const int e = blockIdx.z;
  int off = 0, cnt = M;
  if (counts) { cnt = counts[e]; off = offs[e]; }
  const int rt = blockIdx.y << 6;
  if (rt >= cnt) return;
  const int bn = blockIdx.x << 7;
  const unsigned short* bh = Bh + (size_t)e * wstride;
  const unsigned short* bl = Bl + (size_t)e * wstride;

  // LDS row pitch = 40 ushorts (80 B): 16B-aligned, ~2-way bank pattern.
  __shared__ unsigned short Ahs[64 * 40];
  __shared__ unsigned short Als[64 * 40];
  __shared__ unsigned short Bhs[128 * 40];
  __shared__ unsigned short Bls[128 * 40];

  const int tid = threadIdx.x;
  const int lane = tid & 63;
  const int widx = tid >> 6;
  const int wm = widx >> 1, wn = widx & 1;

  int arow[2];
  #pragma unroll
  for (int p = 0; p < 2; p++) {
    int g = rt + (tid >> 3) + (p << 5);
    if (g >= cnt) g = cnt - 1;
    arow[p] = gather ? gather[off + g] : (off + g);
  }
  const int kcol = (tid & 7) << 2;

  f32x4 acc[2][4] = {};
  const int nK = K >> 5;

  for (int kt = 0; kt < nK; kt++) {
    const int k0 = kt << 5;
    // ---- stage A: fp32 -> split bf16 ----
    #pragma unroll
    for (int p = 0; p < 2; p++) {
      int r = (tid >> 3) + (p << 5);
      float4 v = *(const float4*)(A + (size_t)arow[p] * lda + k0 + kcol);
      unsigned h0, h1, h2, h3, l0, l1, l2, l3;
      split2(v.x, h0, l0); split2(v.y, h1, l1);
      split2(v.z, h2, l2); split2(v.w, h3, l3);
      uint2 hp, lp;
      hp.x = h0 | (h1 << 16); hp.y = h2 | (h3 << 16);
      lp.x = l0 | (l1 << 16); lp.y = l2 | (l3 << 16);
      int byteoff = r * 80 + (kcol << 1);
      *(uint2*)((char*)Ahs + byteoff) = hp;
      *(uint2*)((char*)Als + byteoff) = lp;
    }
    // ---- stage B: pre-split bf16, straight copy ----
    #pragma unroll
    for (int q = 0; q < 2; q++) {
      int c = tid + (q << 8);          // 16B chunk id, 0..511
      int n = c >> 2;
      int k8 = (c & 3) << 3;           // element offset within 32-k window
      size_t se = (size_t)(bn + n) * K + k0 + k8;
      int dst = n * 80 + (k8 << 1);
      *(int4*)((char*)Bhs + dst) = *(const int4*)(bh + se);
      *(int4*)((char*)Bls + dst) = *(const int4*)(bl + se);
    }
    __syncthreads();
    // ---- fragments + MFMA ----
    bf16x8 ah[2], al[2];
    #pragma unroll
    for (int i = 0; i < 2; i++) {
      int r = (wm << 5) + (i << 4) + (lane & 15);
      int byteoff = r * 80 + ((lane >> 4) << 4);
      ah[i] = *(const bf16x8*)((const char*)Ahs + byteoff);
      al[i] = *(const bf16x8*)((const char*)Als + byteoff);
    }
    #pragma unroll
    for (int j = 0; j < 4; j++) {
      int rb = (wn << 6) + (j << 4) + (lane & 15);
      int byteoff = rb * 80 + ((lane >> 4) << 4);
      bf16x8 bhf = *(const bf16x8*)((const char*)Bhs + byteoff);
      bf16x8 blf = *(const bf16x8*)((const char*)Bls + byteoff);
      #pragma unroll
      for (int i = 0; i < 2; i++) {
        acc[i][j] = __builtin_amdgcn_mfma_f32_16x16x32_bf16(ah[i], bhf, acc[i][j], 0, 0, 0);
        acc[i][j] = __builtin_amdgcn_mfma_f32_16x16x32_bf16(ah[i], blf, acc[i][j], 0, 0, 0);
        acc[i][j] = __builtin_amdgcn_mfma_f32_16x16x32_bf16(al[i], bhf, acc[i][j], 0, 0, 0);
      }
    }
    __syncthreads();
  }
  // ---- store (C/D: col=lane&15, row=(lane>>4)*4+rr) ----
  #pragma unroll
  for (int j = 0; j < 4; j++) {
    int col = bn + (wn << 6) + (j << 4) + (lane & 15);
    if (col < N) {
      #pragma unroll
      for (int i = 0; i < 2; i++) {
        #pragma unroll
        for (int rr = 0; rr < 4; rr++) {
          int rl = rt + (wm << 5) + (i << 4) + ((lane >> 4) << 2) + rr;
          if (rl < cnt) {
            size_t ci = (size_t)(off + rl) * ldc + col;
            float v = acc[i][j][rr];
            if (R) v += R[ci];
            C[ci] = v;
          }
        }
      }
    }
  }
}

// ---------------- rope: q[..., 64:96] per head (in-place) + k_pe -----------
__global__ __launch_bounds__(256) void k_rope(
    float* __restrict__ q, const float* __restrict__ kva, float* __restrict__ kp,
    const float* __restrict__ cosb, const float* __restrict__ sinb) {
  int gid = blockIdx.x * 256 + threadIdx.x;
  if (gid >= 1024 * 17 * 16) return;
  int i = gid & 15;
  int rem = gid >> 4;
  int hh = rem % 17;
  int t = rem / 17;
  int s = t & 255;
  float c = cosb[s * 16 + i], sn = sinb[s * 16 + i];
  if (hh < 16) {
    float* p = q + (size_t)t * 1536 + hh * 96 + 64 + 2 * i;
    float a = p[0], bb = p[1];
    p[0] = a * c - bb * sn;
    p[1] = a * sn + bb * c;
  } else {
    const float* p = kva + (size_t)t * 288 + 256 + 2 * i;
    float a = p[0], bb = p[1];
    kp[t * 32 + 2 * i] = a * c - bb * sn;
    kp[t * 32 + 2 * i + 1] = a * sn + bb * c;
  }
}

// ---------------- flash attention, 32 q-rows x 64-key tiles ----------------
__global__ __launch_bounds__(256) void k_attn(
    const float* __restrict__ q, const float* __restrict__ kv,
    const float* __restrict__ kp, float* __restrict__ out) {
  const int qt = blockIdx.x, h = blockIdx.y, b = blockIdx.z;
  __shared__ float Qs[32][97];
  __shared__ float Ks[64][97];
  __shared__ float Vs[64][65];
  __shared__ float Ps[32][65];
  const int tid = threadIdx.x, tx = tid & 15, ty = tid >> 4;
  const int qrow0 = b * 256 + qt * 32;
  for (int idx = tid; idx < 32 * 24; idx += 256) {
    int r = idx / 24, c4 = (idx % 24) << 2;
    float4 v = *(const float4*)(q + (size_t)(qrow0 + r) * 1536 + h * 96 + c4);
    Qs[r][c4 + 0] = v.x * SCALE_ATTN; Qs[r][c4 + 1] = v.y * SCALE_ATTN;
    Qs[r][c4 + 2] = v.z * SCALE_ATTN; Qs[r][c4 + 3] = v.w * SCALE_ATTN;
  }
  float acc[2][4] = {};
  float mrow[2] = {-1e30f, -1e30f};
  float lrow[2] = {0.f, 0.f};
  const int nkt = (qt * 32 + 31) / 64 + 1;
  for (int kt = 0; kt < nkt; kt++) {
    __syncthreads();
    const int krow0 = b * 256 + kt * 64;
    for (int idx = tid; idx < 64 * 16; idx += 256) {
      int r = idx >> 4, c4 = (idx & 15) << 2;
      float4 v = *(const float4*)(kv + (size_t)(krow0 + r) * 2048 + h * 128 + c4);
      Ks[r][c4 + 0] = v.x; Ks[r][c4 + 1] = v.y; Ks[r][c4 + 2] = v.z; Ks[r][c4 + 3] = v.w;
    }
    for (int idx = tid; idx < 64 * 8; idx += 256) {
      int r = idx >> 3, c4 = (idx & 7) << 2;
      float4 v = *(const float4*)(kp + (size_t)(krow0 + r) * 32 + c4);
      Ks[r][64 + c4 + 0] = v.x; Ks[r][64 + c4 + 1] = v.y;
      Ks[r][64 + c4 + 2] = v.z; Ks[r][64 + c4 + 3] = v.w;
    }
    for (int idx = tid; idx < 64 * 16; idx += 256) {
      int r = idx >> 4, c4 = (idx & 15) << 2;
      float4 v = *(const float4*)(kv + (size_t)(krow0 + r) * 2048 + h * 128 + 64 + c4);
      Vs[r][c4 + 0] = v.x; Vs[r][c4 + 1] = v.y; Vs[r][c4 + 2] = v.z; Vs[r][c4 + 3] = v.w;
    }
    __syncthreads();
    float s[2][4] = {};
    for (int d = 0; d < 96; d++) {
      float a0 = Qs[(ty << 1) + 0][d];
      float a1 = Qs[(ty << 1) + 1][d];
      float b0 = Ks[(tx << 2) + 0][d];
      float b1 = Ks[(tx << 2) + 1][d];
      float b2 = Ks[(tx << 2) + 2][d];
      float b3 = Ks[(tx << 2) + 3][d];
      s[0][0] = fmaf(a0, b0, s[0][0]); s[0][1] = fmaf(a0, b1, s[0][1]);
      s[0][2] = fmaf(a0, b2, s[0][2]); s[0][3] = fmaf(a0, b3, s[0][3]);
      s[1][0] = fmaf(a1, b0, s[1][0]); s[1][1] = fmaf(a1, b1, s[1][1]);
      s[1][2] = fmaf(a1, b2, s[1][2]); s[1][3] = fmaf(a1, b3, s[1][3]);
    }
    #pragma unroll
    for (int i = 0; i < 2; i++) {
      int qg = qt * 32 + (ty << 1) + i;
      #pragma unroll
      for (int j = 0; j < 4; j++) {
        int kg = kt * 64 + (tx << 2) + j;
        if (kg > qg) s[i][j] = -1e30f;
      }
    }
    #pragma unroll
    for (int i = 0; i < 2; i++) {
      float mx = fmaxf(fmaxf(s[i][0], s[i][1]), fmaxf(s[i][2], s[i][3]));
      mx = fmaxf(mx, __shfl_xor(mx, 1));
      mx = fmaxf(mx, __shfl_xor(mx, 2));
      mx = fmaxf(mx, __shfl_xor(mx, 4));
      mx = fmaxf(mx, __shfl_xor(mx, 8));
      float mnew = fmaxf(mrow[i], mx);
      float sc = expf(mrow[i] - mnew);
      float psum = 0.f;
      #pragma unroll
      for (int j = 0; j < 4; j++) {
        float p = expf(s[i][j] - mnew);
        Ps[(ty << 1) + i][(tx << 2) + j] = p;
        psum += p;
      }
      psum += __shfl_xor(psum, 1);
      psum += __shfl_xor(psum, 2);
      psum += __shfl_xor(psum, 4);
      psum += __shfl_xor(psum, 8);
      lrow[i] = lrow[i] * sc + psum;
      mrow[i] = mnew;
      #pragma unroll
      for (int j = 0; j < 4; j++) acc[i][j] *= sc;
    }
    __syncthreads();
    for (int kc = 0; kc < 64; kc++) {
      float p0 = Ps[(ty << 1) + 0][kc];
      float p1 = Ps[(ty << 1) + 1][kc];
      float v0 = Vs[kc][(tx << 2) + 0];
      float v1 = Vs[kc][(tx << 2) + 1];
      float v2 = Vs[kc][(tx << 2) + 2];
      float v3 = Vs[kc][(tx << 2) + 3];
      acc[0][0] = fmaf(p0, v0, acc[0][0]); acc[0][1] = fmaf(p0, v1, acc[0][1]);
      acc[0][2] = fmaf(p0, v2, acc[0][2]); acc[0][3] = fmaf(p0, v3, acc[0][3]);
      acc[1][0] = fmaf(p1, v0, acc[1][0]); acc[1][1] = fmaf(p1, v1, acc[1][1]);
      acc[1][2] = fmaf(p1, v2, acc[1][2]); acc[1][3] = fmaf(p1, v3, acc[1][3]);
    }
  }
  #pragma unroll
  for (int i = 0; i < 2; i++) {
    float inv = 1.f / lrow[i];
    float4 o;
    o.x = acc[i][0] * inv; o.y = acc[i][1] * inv;
    o.z = acc[i][2] * inv; o.w = acc[i][3] * inv;
    *(float4*)(out + (size_t)(qrow0 + (ty << 1) + i) * 1024 + h * 64 + (tx << 2)) = o;
  }
}

// ---------------- router / MoE bookkeeping --------------------------------
__global__ __launch_bounds__(256) void k_router(
    const float* __restrict__ t_, const float* __restrict__ Wr,
    int* __restrict__ tok_idx, float* __restrict__ tok_w, int* __restrict__ counts) {
  int wv = threadIdx.x >> 6, lane = threadIdx.x & 63;
  int tok = blockIdx.x * 4 + wv;
  const float* x = t_ + (size_t)tok * 1024;
  float a[8] = {};
  for (int d = lane; d < 1024; d += 64) {
    float xv = x[d];
    const float* wr = Wr + d * 8;
    #pragma unroll
    for (int e = 0; e < 8; e++) a[e] = fmaf(xv, wr[e], a[e]);
  }
  #pragma unroll
  for (int e = 0; e < 8; e++) {
    #pragma unroll
    for (int off = 32; off > 0; off >>= 1) a[e] += __shfl_xor(a[e], off);
  }
  if (lane == 0) {
    float m = a[0];
    #pragma unroll
    for (int e = 1; e < 8; e++) m = fmaxf(m, a[e]);
    float p[8];
    #pragma unroll
    for (int e = 0; e < 8; e++) p[e] = expf(a[e] - m);
    int i0 = 0;
    #pragma unroll
    for (int e = 1; e < 8; e++) if (p[e] > p[i0]) i0 = e;
    int i1 = (i0 == 0) ? 1 : 0;
    #pragma unroll
    for (int e = 0; e < 8; e++) if (e != i0 && p[e] > p[i1]) i1 = e;
    float denom = p[i0] + p[i1];
    tok_idx[tok * 2] = i0; tok_idx[tok * 2 + 1] = i1;
    tok_w[tok * 2] = p[i0] / denom; tok_w[tok * 2 + 1] = p[i1] / denom;
    atomicAdd(&counts[i0], 1);
    atomicAdd(&counts[i1], 1);
  }
}

__global__ void k_zero8(int* counts) { if (threadIdx.x < 8) counts[threadIdx.x] = 0; }

__global__ void k_scan(const int* __restrict__ counts, int* __restrict__ offs,
                       int* __restrict__ cursor) {
  if (threadIdx.x == 0) {
    int s = 0;
    for (int e = 0; e < 8; e++) { offs[e] = s; cursor[e] = s; s += counts[e]; }
  }
}

__global__ __launch_bounds__(256) void k_assign(
    const int* __restrict__ tok_idx, int* __restrict__ cursor,
    int* __restrict__ gather, int* __restrict__ pos) {
  int t = blockIdx.x * 256 + threadIdx.x;
  if (t >= 1024) return;
  #pragma unroll
  for (int s2 = 0; s2 < 2; s2++) {
    int e = tok_idx[t * 2 + s2];
    int p = atomicAdd(&cursor[e], 1);
    gather[p] = t;
    pos[t * 2 + s2] = p;
  }
}

// out[r*outPitch+m] = silu(in[r*inPitch+m]) * in[r*inPitch+half+m]
// (in-place safe: each output location is only that thread's own input)
__global__ __launch_bounds__(256) void k_silu2(
    const float* __restrict__ in, float* __restrict__ out,
    int total, int sh, int inPitch, int outPitch) {
  int half = 1 << sh;
  for (int i = blockIdx.x * 256 + threadIdx.x; i < total; i += gridDim.x * 256) {
    int r = i >> sh, m = i & (half - 1);
    float a = in[(size_t)r * inPitch + m];
    float b = in[(size_t)r * inPitch + half + m];
    out[(size_t)r * outPitch + m] = (a / (1.f + expf(-a))) * b;
  }
}

__global__ __launch_bounds__(256) void k_combine(
    float* __restrict__ hs, const float* __restrict__ sho,
    const float* __restrict__ routed, const int* __restrict__ pos,
    const float* __restrict__ tok_w) {
  int i = blockIdx.x * 256 + threadIdx.x;
  if (i >= 1024 * 1024) return;
  int t = i >> 10, d = i & 1023;
  float v = hs[i] + sho[i];
  v = fmaf(tok_w[t * 2], routed[(size_t)pos[t * 2] * 1024 + d], v);
  v = fmaf(tok_w[t * 2 + 1], routed[(size_t)pos[t * 2 + 1] * 1024 + d], v);
  hs[i] = v;
}

__global__ __launch_bounds__(256) void k_outproj(
    const float* __restrict__ h, const float* __restrict__ W, float* __restrict__ out) {
  int t = blockIdx.x;
  float s = 0.f;
  for (int d = threadIdx.x; d < 1024; d += 256) s = fmaf(h[(size_t)t * 1024 + d], W[d], s);
  __shared__ float red[256];
  red[threadIdx.x] = s;
  __syncthreads();
  #pragma unroll
  for (int st = 128; st > 0; st >>= 1) {
    if (threadIdx.x < st) red[threadIdx.x] += red[threadIdx.x + st];
    __syncthreads();
  }
  if (threadIdx.x == 0) out[t] = red[0];
}

// ---------------------------------------------------------------------------
extern "C" void kernel_launch(void* const* d_in, const int* in_sizes, int n_in,
                              void* d_out, int out_size, void* d_ws, size_t ws_size,
                              hipStream_t stream) {
  (void)in_sizes; (void)n_in; (void)out_size;
  const float* x        = (const float*)d_in[0];
  const float* rope_cos = (const float*)d_in[1];
  const float* rope_sin = (const float*)d_in[2];
  const float* W_in     = (const float*)d_in[3];
  const float* attn_nw  = (const float*)d_in[4];
  const float* Wqa      = (const float*)d_in[5];
  const float* q_nw     = (const float*)d_in[6];
  const float* Wqb      = (const float*)d_in[7];
  const float* Wkva     = (const float*)d_in[8];
  const float* kv_nw    = (const float*)d_in[9];
  const float* Wkvb     = (const float*)d_in[10];
  const float* Wo       = (const float*)d_in[11];
  const float* moe_nw   = (const float*)d_in[12];
  const float* Wr       = (const float*)d_in[13];
  const float* We1      = (const float*)d_in[14];
  const float* We3      = (const float*)d_in[15];
  const float* We2      = (const float*)d_in[16];
  const float* Ws1      = (const float*)d_in[17];
  const float* Ws3      = (const float*)d_in[18];
  const float* Ws2      = (const float*)d_in[19];
  const float* fin_nw   = (const float*)d_in[20];
  const float* W_out    = (const float*)d_in[21];
  float* out = (float*)d_out;

  if (ws_size < (size_t)97000000) return;  // need ~96.8 MB

  // ---- workspace layout ----
  float* hs = (float*)d_ws;                               // 1048576 f
  float* h  = hs + 1048576;                               // 1048576 f
  unsigned short* wbin = (unsigned short*)(h + 1048576);  // 131072 us
  unsigned short* wb   = wbin + 131072;                   // 25165824 us (50.3MB)
  float* ar = (float*)(wb + 25165824);
  // attention phase
  float* qa   = ar;                   // 393216
  float* q    = qa + 393216;          // 1572864
  float* kva  = q + 1572864;          // 294912
  float* ckv  = kva + 294912;         // 262144
  float* kv   = ckv + 262144;         // 2097152
  float* kp   = kv + 2097152;         // 32768
  float* attnO= kp + 32768;           // 1048576 (end 5701632)
  // MoE phase (aliases attn phase)
  float* g      = ar;                 // 2048*1024 (silu in-place -> cols 0:512)
  float* routed = g + 2097152;        // 2048*1024
  float* s      = routed + 2097152;   // 1024*4096 (silu in-place -> cols 0:2048)
  float* sho    = s + 4194304;        // 1024*1024 (end 9437184)
  float* arena_end = ar + 9437184;
  int*   counts  = (int*)arena_end;
  int*   offs    = counts + 8;
  int*   cursor  = offs + 8;
  int*   tok_idx = cursor + 8;        // 2048
  int*   pos     = tok_idx + 2048;    // 2048
  int*   gatherA = pos + 2048;        // 2048
  float* tok_w   = (float*)(gatherA + 2048);  // 2048

  dim3 thr(256);

  // ---- convert W_in + input GEMM ----
  {
    CvArgs ca{}; ca.nd = 1;
    ca.d[0] = {W_in, wbin, wbin + 65536, 64, 1024, 0, 0, 0, 64, 2};
    k_conv<<<64, thr, 0, stream>>>(ca);
  }
  k_gsp<<<dim3(8, 16, 1), thr, 0, stream>>>(x, 64, nullptr, nullptr, nullptr,
      wbin, wbin + 65536, 0L, 64, 1024, 1024, hs, 1024, nullptr);

  for (int l = 0; l < 4; l++) {
    // ================= phase 1: attention weights =================
    // layout (ushort offsets, hi then lo contiguous per matrix):
    // Wqa@0 z393216 | Wqb@786432 z589824 | Wkva@1966080 z393216 |
    // Wkvb@2752512 z524288 | Wo@3801088 z1048576  (end 5898240)
    {
      CvArgs ca{}; ca.nd = 5;
      ca.d[0] = {Wqa + (size_t)l * 393216, wb + 0, wb + 393216,
                 1024, 384, 0, 0, 0, 384, 32};
      ca.d[1] = {Wqb + (size_t)l * 589824, wb + 786432, wb + 786432 + 589824,
                 384, 1536, 0, 0, 384, 576, 12};
      ca.d[2] = {Wkva + (size_t)l * 294912, wb + 1966080, wb + 1966080 + 393216,
                 1024, 288, 0, 0, 960, 384, 32};
      ca.d[3] = {Wkvb + (size_t)l * 524288, wb + 2752512, wb + 2752512 + 524288,
                 256, 2048, 0, 0, 1344, 512, 8};
      ca.d[4] = {Wo + (size_t)l * 1048576, wb + 3801088, wb + 3801088 + 1048576,
                 1024, 1024, 0, 0, 1856, 1024, 32};
      k_conv<<<2880, thr, 0, stream>>>(ca);
    }
    k_rms<<<1024, thr, 0, stream>>>(hs, 1024, attn_nw + l * 1024, h, 1024, 1024);
    k_gsp<<<dim3(3, 16, 1), thr, 0, stream>>>(h, 1024, nullptr, nullptr, nullptr,
        wb + 0, wb + 393216, 0L, 1024, 384, 1024, qa, 384, nullptr);
    k_rms<<<1024, thr, 0, stream>>>(qa, 384, q_nw + l * 384, qa, 384, 384);
    k_gsp<<<dim3(12, 16, 1), thr, 0, stream>>>(qa, 384, nullptr, nullptr, nullptr,
        wb + 786432, wb + 1376256, 0L, 384, 1536, 1024, q, 1536, nullptr);
    k_gsp<<<dim3(3, 16, 1), thr, 0, stream>>>(h, 1024, nullptr, nullptr, nullptr,
        wb + 1966080, wb + 2359296, 0L, 1024, 288, 1024, kva, 288, nullptr);
    k_rms<<<1024, thr, 0, stream>>>(kva, 288, kv_nw + l * 256, ckv, 256, 256);
    k_gsp<<<dim3(16, 16, 1), thr, 0, stream>>>(ckv, 256, nullptr, nullptr, nullptr,
        wb + 2752512, wb + 3276800, 0L, 256, 2048, 1024, kv, 2048, nullptr);
    k_rope<<<1088, thr, 0, stream>>>(q, kva, kp, rope_cos, rope_sin);
    k_attn<<<dim3(8, 16, 4), thr, 0, stream>>>(q, kv, kp, attnO);
    k_gsp<<<dim3(8, 16, 1), thr, 0, stream>>>(attnO, 1024, nullptr, nullptr, nullptr,
        wb + 3801088, wb + 4849664, 0L, 1024, 1024, 1024, hs, 1024, hs);

    // ---- router ----
    k_rms<<<1024, thr, 0, stream>>>(hs, 1024, moe_nw + l * 1024, h, 1024, 1024);
    k_zero8<<<1, 64, 0, stream>>>(counts);
    k_router<<<256, thr, 0, stream>>>(h, Wr + (size_t)l * 8192, tok_idx, tok_w, counts);
    k_scan<<<1, 64, 0, stream>>>(counts, offs, cursor);
    k_assign<<<4, thr, 0, stream>>>(tok_idx, cursor, gatherA, pos);

    // ================= phase 2: routed experts =================
    // W13 [E][1024n][1024k]: hi@0, lo@8388608 (We1 rows 0:512, We3 512:1024)
    // We2 [E][1024n][512k]: hi@16777216, lo@20971520  (end 25165824)
    {
      CvArgs ca{}; ca.nd = 3;
      ca.d[0] = {We1 + (size_t)l * 4194304, wb + 0, wb + 8388608,
                 1024, 512, 524288, 1048576, 0, 512, 32};
      ca.d[1] = {We3 + (size_t)l * 4194304, wb + 524288, wb + 8388608 + 524288,
                 1024, 512, 524288, 1048576, 4096, 512, 32};
      ca.d[2] = {We2 + (size_t)l * 4194304, wb + 16777216, wb + 20971520,
                 512, 1024, 524288, 524288, 8192, 512, 16};
      k_conv<<<12288, thr, 0, stream>>>(ca);
    }
    k_gsp<<<dim3(8, 32, 8), thr, 0, stream>>>(h, 1024, gatherA, offs, counts,
        wb + 0, wb + 8388608, 1048576L, 1024, 1024, 0, g, 1024, nullptr);
    k_silu2<<<1024, thr, 0, stream>>>(g, g, 2048 * 512, 9, 1024, 1024);
    k_gsp<<<dim3(8, 32, 8), thr, 0, stream>>>(g, 1024, nullptr, offs, counts,
        wb + 16777216, wb + 20971520, 524288L, 512, 1024, 0, routed, 1024, nullptr);

    // ================= phase 3: shared MLP =================
    // Ws13 [4096n][1024k]: hi@0, lo@4194304 (Ws1 rows 0:2048, Ws3 2048:4096)
    // Ws2 [1024n][2048k]: hi@8388608, lo@10485760  (end 12582912)
    {
      CvArgs ca{}; ca.nd = 3;
      ca.d[0] = {Ws1 + (size_t)l * 2097152, wb + 0, wb + 4194304,
                 1024, 2048, 0, 0, 0, 2048, 32};
      ca.d[1] = {Ws3 + (size_t)l * 2097152, wb + 2097152, wb + 4194304 + 2097152,
                 1024, 2048, 0, 0, 2048, 2048, 32};
      ca.d[2] = {Ws2 + (size_t)l * 2097152, wb + 8388608, wb + 10485760,
                 2048, 1024, 0, 0, 4096, 2048, 64};
      k_conv<<<6144, thr, 0, stream>>>(ca);
    }
    k_gsp<<<dim3(32, 16, 1), thr, 0, stream>>>(h, 1024, nullptr, nullptr, nullptr,
        wb + 0, wb + 4194304, 0L, 1024, 4096, 1024, s, 4096, nullptr);
    k_silu2<<<2048, thr, 0, stream>>>(s, s, 1024 * 2048, 11, 4096, 4096);
    k_gsp<<<dim3(8, 16, 1), thr, 0, stream>>>(s, 4096, nullptr, nullptr, nullptr,
        wb + 8388608, wb + 10485760, 0L, 2048, 1024, 1024, sho, 1024, nullptr);
    k_combine<<<4096, thr, 0, stream>>>(hs, sho, routed, pos, tok_w);
  }

  // ---- final norm + output projection ----
  k_rms<<<1024, thr, 0, stream>>>(hs, 1024, fin_nw, h, 1024, 1024);
  k_outproj<<<1024, thr, 0, stream>>>(h, W_out, out);
}